// Round 1
// baseline (250.182 us; speedup 1.0000x reference)
//
#include <hip/hip_runtime.h>
#include <stdint.h>

#define GDIM   512
#define HID    150
#define HIDP   160    // HID padded to multiple of 16
#define NROWS  12000
#define KP1    31     // KMAX+1

typedef __attribute__((ext_vector_type(8))) short bf16x8;
typedef __attribute__((ext_vector_type(4))) float f32x4;

__device__ __forceinline__ unsigned short f2bf(float x){
    unsigned int u = __float_as_uint(x);
    return (unsigned short)((u + 0x7fffu + ((u >> 16) & 1u)) >> 16);
}

// ---------------------------------------------------------------- prep: W^T cast to bf16, zero-padded
__global__ void k_castT(const float* __restrict__ W, unsigned short* __restrict__ out,
                        int Ntot, int K, int nvalid, int kvalid, int ld, int koff){
    int idx = blockIdx.x * blockDim.x + threadIdx.x;
    int total = Ntot * K;
    if (idx >= total) return;
    int n = idx / K, k = idx - n * K;
    float v = (n < nvalid && k < kvalid) ? W[(size_t)(k + koff) * ld + n] : 0.f;
    out[idx] = f2bf(v);
}

// ---------------------------------------------------------------- prep: phi table (210 combos) @ W1_phi + b1
__global__ void k_phiw(const float* __restrict__ de, const float* __restrict__ ge,
                       const float* __restrict__ se, const float* __restrict__ W1,
                       const float* __restrict__ b1, float* __restrict__ PhiW){
    int c = blockIdx.x;      // 0..209
    int h = threadIdx.x;
    if (h >= HIDP) return;
    int si = c % 3, gi2 = (c / 3) % 7, di = c / 21;
    float acc = 0.f;
    if (h < HID){
        acc = b1[h];
        #pragma unroll
        for (int d = 0; d < 20; d++) acc += de[di*20 + d] * W1[(size_t)(1536 + d) * HID + h];
        #pragma unroll
        for (int d = 0; d < 20; d++) acc += ge[gi2*20 + d] * W1[(size_t)(1556 + d) * HID + h];
        #pragma unroll
        for (int d = 0; d < 20; d++) acc += se[si*20 + d] * W1[(size_t)(1576 + d) * HID + h];
    }
    PhiW[c * HIDP + h] = acc;
}

// ---------------------------------------------------------------- phase 1: Am = g_i@W1_a, Aa = g_i@W1_b  (blockIdx.y selects)
__global__ __launch_bounds__(256) void k_proj(const float* __restrict__ g_i,
                                              const unsigned short* __restrict__ WT,
                                              float* __restrict__ out){
    const unsigned short* Wh = WT + (size_t)blockIdx.y * 160 * 512;
    float* outh = out + (size_t)blockIdx.y * NROWS * HIDP;
    __shared__ short A_lds[64 * 72];
    __shared__ short B_lds[160 * 72];
    int tid = threadIdx.x, lane = tid & 63, w = tid >> 6;
    int row0 = blockIdx.x * 64;
    f32x4 acc[10];
    #pragma unroll
    for (int t = 0; t < 10; t++) acc[t] = (f32x4){0.f, 0.f, 0.f, 0.f};

    for (int kt = 0; kt < GDIM; kt += 64){
        #pragma unroll
        for (int i = 0; i < 2; i++){
            int c = tid + 256 * i; int r = c >> 3, off = c & 7;
            int row = row0 + r; if (row > NROWS - 1) row = NROWS - 1;
            const float4* gp = reinterpret_cast<const float4*>(g_i + (size_t)row * GDIM + kt + off * 8);
            float4 x0 = gp[0], x1 = gp[1];
            bf16x8 v;
            v[0]=(short)f2bf(x0.x); v[1]=(short)f2bf(x0.y); v[2]=(short)f2bf(x0.z); v[3]=(short)f2bf(x0.w);
            v[4]=(short)f2bf(x1.x); v[5]=(short)f2bf(x1.y); v[6]=(short)f2bf(x1.z); v[7]=(short)f2bf(x1.w);
            *reinterpret_cast<bf16x8*>(&A_lds[r * 72 + off * 8]) = v;
        }
        #pragma unroll
        for (int i = 0; i < 5; i++){
            int c = tid + 256 * i; int n = c >> 3, off = c & 7;
            *reinterpret_cast<bf16x8*>(&B_lds[n * 72 + off * 8]) =
                *reinterpret_cast<const bf16x8*>(&Wh[(size_t)n * 512 + kt + off * 8]);
        }
        __syncthreads();
        #pragma unroll
        for (int kh = 0; kh < 2; kh++){
            bf16x8 a = *reinterpret_cast<const bf16x8*>(&A_lds[(16*w + (lane & 15)) * 72 + kh*32 + 8*(lane >> 4)]);
            #pragma unroll
            for (int t = 0; t < 10; t++){
                bf16x8 b = *reinterpret_cast<const bf16x8*>(&B_lds[(16*t + (lane & 15)) * 72 + kh*32 + 8*(lane >> 4)]);
                acc[t] = __builtin_amdgcn_mfma_f32_16x16x32_bf16(a, b, acc[t], 0, 0, 0);
            }
        }
        __syncthreads();
    }
    #pragma unroll
    for (int t = 0; t < 10; t++){
        #pragma unroll
        for (int i = 0; i < 4; i++){
            int r = 16*w + 4*(lane >> 4) + i;
            int row = row0 + r;
            if (row < NROWS) outh[(size_t)row * HIDP + 16*t + (lane & 15)] = acc[t][i];
        }
    }
}

// ---------------------------------------------------------------- phase 2+3 fused: product GEMM + epilogue + layer2 GEMM + W3 dot + scatter
__global__ __launch_bounds__(256) void k_fused(
    const float* __restrict__ g_i, const float* __restrict__ ms,
    const unsigned short* __restrict__ W1cT, const unsigned short* __restrict__ W2T,
    const float* __restrict__ PhiW, const float* __restrict__ Am, const float* __restrict__ Aa,
    const float* __restrict__ W3, const float* __restrict__ b2, const float* __restrict__ b3,
    const int* __restrict__ mention_ids, const int* __restrict__ antecedent_ids,
    const int* __restrict__ dist_idx, const int* __restrict__ genre_idx, const int* __restrict__ spk_idx,
    const int* __restrict__ seg_ids, const int* __restrict__ pos_in_seg,
    float* __restrict__ dense, int P)
{
    __shared__ short smem[17152];          // 34304 B, regions time-shared
    short* A_lds  = smem;                  // [64][72]   GEMM1
    short* B_lds  = smem + 4608;           // [160][72]  GEMM1
    short* H1_lds = smem;                  // [64][168]  GEMM2 A (overlaps dead A/B)
    short* B2_lds = smem + 10752;          // [160][40]  GEMM2 B
    __shared__ int mids[64], aids[64], combos[64];

    int tid = threadIdx.x, lane = tid & 63, w = tid >> 6;
    int p0 = blockIdx.x * 64;

    if (tid < 64){
        int p = p0 + tid; int pc = (p < P) ? p : P - 1;
        mids[tid]   = mention_ids[pc];
        aids[tid]   = antecedent_ids[pc];
        combos[tid] = (dist_idx[pc] * 7 + genre_idx[pc]) * 3 + spk_idx[pc];
    }
    __syncthreads();

    f32x4 acc1[10];
    #pragma unroll
    for (int t = 0; t < 10; t++) acc1[t] = (f32x4){0.f, 0.f, 0.f, 0.f};

    for (int kt = 0; kt < GDIM; kt += 64){
        // A tile: products (i_g ⊙ j_g), gathered, cast bf16
        #pragma unroll
        for (int i = 0; i < 2; i++){
            int c = tid + 256 * i; int r = c >> 3, off = c & 7;
            const float4* gm = reinterpret_cast<const float4*>(g_i + (size_t)mids[r] * GDIM + kt + off * 8);
            const float4* ga = reinterpret_cast<const float4*>(g_i + (size_t)aids[r] * GDIM + kt + off * 8);
            float4 m0 = gm[0], m1 = gm[1], a0 = ga[0], a1 = ga[1];
            bf16x8 v;
            v[0]=(short)f2bf(m0.x*a0.x); v[1]=(short)f2bf(m0.y*a0.y);
            v[2]=(short)f2bf(m0.z*a0.z); v[3]=(short)f2bf(m0.w*a0.w);
            v[4]=(short)f2bf(m1.x*a1.x); v[5]=(short)f2bf(m1.y*a1.y);
            v[6]=(short)f2bf(m1.z*a1.z); v[7]=(short)f2bf(m1.w*a1.w);
            *reinterpret_cast<bf16x8*>(&A_lds[r * 72 + off * 8]) = v;
        }
        // B tile: W1c^T chunk (pre-cast bf16)
        #pragma unroll
        for (int i = 0; i < 5; i++){
            int c = tid + 256 * i; int n = c >> 3, off = c & 7;
            *reinterpret_cast<bf16x8*>(&B_lds[n * 72 + off * 8]) =
                *reinterpret_cast<const bf16x8*>(&W1cT[(size_t)n * 512 + kt + off * 8]);
        }
        __syncthreads();
        #pragma unroll
        for (int kh = 0; kh < 2; kh++){
            bf16x8 a = *reinterpret_cast<const bf16x8*>(&A_lds[(16*w + (lane & 15)) * 72 + kh*32 + 8*(lane >> 4)]);
            #pragma unroll
            for (int t = 0; t < 10; t++){
                bf16x8 b = *reinterpret_cast<const bf16x8*>(&B_lds[(16*t + (lane & 15)) * 72 + kh*32 + 8*(lane >> 4)]);
                acc1[t] = __builtin_amdgcn_mfma_f32_16x16x32_bf16(a, b, acc1[t], 0, 0, 0);
            }
        }
        __syncthreads();
    }

    // epilogue 1: + Am + Aa + PhiW(+b1), relu, -> H1 in LDS (bf16)
    #pragma unroll
    for (int i = 0; i < 4; i++){
        int r = 16*w + 4*(lane >> 4) + i;
        int mid = mids[r], aid = aids[r], cmb = combos[r];
        #pragma unroll
        for (int t = 0; t < 10; t++){
            int h = 16*t + (lane & 15);
            float v = acc1[t][i] + Am[(size_t)mid * HIDP + h] + Aa[(size_t)aid * HIDP + h]
                    + PhiW[cmb * HIDP + h];
            v = fmaxf(v, 0.f);
            H1_lds[r * 168 + h] = (short)f2bf(v);
        }
    }
    __syncthreads();

    // GEMM2: H2 = H1 @ W2 (K = 160, in 5 chunks of 32)
    f32x4 acc2[10];
    #pragma unroll
    for (int t = 0; t < 10; t++) acc2[t] = (f32x4){0.f, 0.f, 0.f, 0.f};

    for (int kt2 = 0; kt2 < HIDP; kt2 += 32){
        #pragma unroll
        for (int i = 0; i < 3; i++){
            int c = tid + 256 * i;
            if (c < 640){
                int n = c >> 2, off = c & 3;
                *reinterpret_cast<bf16x8*>(&B2_lds[n * 40 + off * 8]) =
                    *reinterpret_cast<const bf16x8*>(&W2T[(size_t)n * HIDP + kt2 + off * 8]);
            }
        }
        __syncthreads();
        bf16x8 a = *reinterpret_cast<const bf16x8*>(&H1_lds[(16*w + (lane & 15)) * 168 + kt2 + 8*(lane >> 4)]);
        #pragma unroll
        for (int t = 0; t < 10; t++){
            bf16x8 b = *reinterpret_cast<const bf16x8*>(&B2_lds[(16*t + (lane & 15)) * 40 + 8*(lane >> 4)]);
            acc2[t] = __builtin_amdgcn_mfma_f32_16x16x32_bf16(a, b, acc2[t], 0, 0, 0);
        }
        __syncthreads();
    }

    // epilogue 2: relu(+b2), dot W3, + mention scores, scatter into dense
    float w3v[10], b2v[10];
    #pragma unroll
    for (int t = 0; t < 10; t++){
        int h = 16*t + (lane & 15);
        w3v[t] = (h < HID) ? W3[h] : 0.f;
        b2v[t] = (h < HID) ? b2[h] : 0.f;
    }
    float b3v = b3[0];
    #pragma unroll
    for (int i = 0; i < 4; i++){
        float s = 0.f;
        #pragma unroll
        for (int t = 0; t < 10; t++) s += fmaxf(acc2[t][i] + b2v[t], 0.f) * w3v[t];
        s += __shfl_xor(s, 1, 16);
        s += __shfl_xor(s, 2, 16);
        s += __shfl_xor(s, 4, 16);
        s += __shfl_xor(s, 8, 16);
        int r = 16*w + 4*(lane >> 4) + i;
        int p = p0 + r;
        if (p < P && (lane & 15) == 0){
            float val = s + b3v + ms[mids[r]] + ms[aids[r]];
            dense[(size_t)seg_ids[p] * KP1 + pos_in_seg[p]] = val;
        }
    }
}

// ---------------------------------------------------------------- phase 4: segment softmax, epsilon slot, 1000 padding
__global__ void k_softmax(const float* __restrict__ dense, const int* __restrict__ seg_lengths,
                          float* __restrict__ out, int S){
    int wid = threadIdx.x >> 6, lane = threadIdx.x & 63;
    int s = blockIdx.x * 4 + wid;
    if (s >= S) return;
    int len = seg_lengths[s];
    float ninf = -__builtin_inff();
    float val = ninf;
    if (lane < KP1) val = (lane < len) ? dense[(size_t)s * KP1 + lane] : ((lane == len) ? 0.f : ninf);
    float m = val;
    #pragma unroll
    for (int msk = 1; msk < 64; msk <<= 1) m = fmaxf(m, __shfl_xor(m, msk));
    float e = expf(val - m);
    float sum = e;
    #pragma unroll
    for (int msk = 1; msk < 64; msk <<= 1) sum += __shfl_xor(sum, msk);
    if (lane < KP1) out[(size_t)s * KP1 + lane] = (lane > len) ? 1000.f : (e / sum);
}

// ---------------------------------------------------------------- launch
extern "C" void kernel_launch(void* const* d_in, const int* in_sizes, int n_in,
                              void* d_out, int out_size, void* d_ws, size_t ws_size,
                              hipStream_t stream){
    const float* g_i        = (const float*)d_in[0];
    const float* ms         = (const float*)d_in[1];
    const float* dist_emb   = (const float*)d_in[2];
    const float* genre_emb  = (const float*)d_in[3];
    const float* spk_emb    = (const float*)d_in[4];
    const float* W1         = (const float*)d_in[5];
    const float* b1         = (const float*)d_in[6];
    const float* W2         = (const float*)d_in[7];
    const float* b2         = (const float*)d_in[8];
    const float* W3         = (const float*)d_in[9];
    const float* b3         = (const float*)d_in[10];
    const int* mention_ids  = (const int*)d_in[11];
    const int* antecedent_ids = (const int*)d_in[12];
    const int* dist_idx     = (const int*)d_in[13];
    const int* genre_idx    = (const int*)d_in[14];
    const int* spk_idx      = (const int*)d_in[15];
    const int* seg_ids      = (const int*)d_in[16];
    const int* pos_in_seg   = (const int*)d_in[17];
    const int* seg_lengths  = (const int*)d_in[18];
    int P = in_sizes[11];
    int S = in_sizes[18];

    char* ws = (char*)d_ws;
    unsigned short* W1abT = (unsigned short*)(ws + 0);         // 320*512*2  = 327680
    unsigned short* W1cT  = (unsigned short*)(ws + 327680);    // 160*512*2  = 163840
    unsigned short* W2T   = (unsigned short*)(ws + 491520);    // 160*160*2  = 51200
    float* PhiW           = (float*)(ws + 542720);             // 210*160*4  = 134400
    float* AmAa           = (float*)(ws + 677120);             // 2*12000*160*4 = 15360000
    float* dense          = (float*)(ws + 16037120);           // 10001*31*4

    // weight prep
    k_castT<<<(160*512 + 255)/256, 256, 0, stream>>>(W1, W1abT,            160, 512, HID, 512, HID, 0);
    k_castT<<<(160*512 + 255)/256, 256, 0, stream>>>(W1, W1abT + 160*512,  160, 512, HID, 512, HID, 512);
    k_castT<<<(160*512 + 255)/256, 256, 0, stream>>>(W1, W1cT,             160, 512, HID, 512, HID, 1024);
    k_castT<<<(160*160 + 255)/256, 256, 0, stream>>>(W2, W2T,              160, 160, HID, HID, HID, 0);
    k_phiw<<<210, 192, 0, stream>>>(dist_emb, genre_emb, spk_emb, W1, b1, PhiW);

    // row projections Am / Aa
    k_proj<<<dim3((NROWS + 63)/64, 2), 256, 0, stream>>>(g_i, W1abT, AmAa);

    // fused pair scorer
    k_fused<<<(P + 63)/64, 256, 0, stream>>>(g_i, ms, W1cT, W2T, PhiW,
        AmAa, AmAa + (size_t)NROWS*HIDP, W3, b2, b3,
        mention_ids, antecedent_ids, dist_idx, genre_idx, spk_idx,
        seg_ids, pos_in_seg, dense, P);

    // segment softmax
    k_softmax<<<(S + 3)/4, 256, 0, stream>>>(dense, seg_lengths, (float*)d_out, S);
}

// Round 2
// 205.174 us; speedup vs baseline: 1.2194x; 1.2194x over previous
//
#include <hip/hip_runtime.h>
#include <stdint.h>

#define GDIM   512
#define HID    150
#define HIDP   160    // HID padded to multiple of 16
#define NROWS  12000
#define KP1    31     // KMAX+1

typedef __attribute__((ext_vector_type(8))) short bf16x8;
typedef __attribute__((ext_vector_type(4))) float f32x4;

__device__ __forceinline__ unsigned short f2bf(float x){
    unsigned int u = __float_as_uint(x);
    return (unsigned short)((u + 0x7fffu + ((u >> 16) & 1u)) >> 16);
}
__device__ __forceinline__ float bf2f(unsigned short u){
    return __uint_as_float(((unsigned int)u) << 16);
}

// ---------------------------------------------------------------- prep: g_i cast to bf16 (12.3 MB table; gathered by k_proj/k_fused)
__global__ void k_cast_g(const float* __restrict__ g, unsigned short* __restrict__ out, int n8){
    int c = blockIdx.x * blockDim.x + threadIdx.x;
    if (c >= n8) return;
    const float4* p = reinterpret_cast<const float4*>(g + (size_t)c * 8);
    float4 x0 = p[0], x1 = p[1];
    bf16x8 v;
    v[0]=(short)f2bf(x0.x); v[1]=(short)f2bf(x0.y); v[2]=(short)f2bf(x0.z); v[3]=(short)f2bf(x0.w);
    v[4]=(short)f2bf(x1.x); v[5]=(short)f2bf(x1.y); v[6]=(short)f2bf(x1.z); v[7]=(short)f2bf(x1.w);
    reinterpret_cast<bf16x8*>(out)[c] = v;
}

// ---------------------------------------------------------------- prep: W^T cast to bf16, zero-padded
__global__ void k_castT(const float* __restrict__ W, unsigned short* __restrict__ out,
                        int Ntot, int K, int nvalid, int kvalid, int ld, int koff){
    int idx = blockIdx.x * blockDim.x + threadIdx.x;
    int total = Ntot * K;
    if (idx >= total) return;
    int n = idx / K, k = idx - n * K;
    float v = (n < nvalid && k < kvalid) ? W[(size_t)(k + koff) * ld + n] : 0.f;
    out[idx] = f2bf(v);
}

// ---------------------------------------------------------------- prep: phi table (210 combos) @ W1_phi + b1
__global__ void k_phiw(const float* __restrict__ de, const float* __restrict__ ge,
                       const float* __restrict__ se, const float* __restrict__ W1,
                       const float* __restrict__ b1, float* __restrict__ PhiW){
    int c = blockIdx.x;      // 0..209
    int h = threadIdx.x;
    if (h >= HIDP) return;
    int si = c % 3, gi2 = (c / 3) % 7, di = c / 21;
    float acc = 0.f;
    if (h < HID){
        acc = b1[h];
        #pragma unroll
        for (int d = 0; d < 20; d++) acc += de[di*20 + d] * W1[(size_t)(1536 + d) * HID + h];
        #pragma unroll
        for (int d = 0; d < 20; d++) acc += ge[gi2*20 + d] * W1[(size_t)(1556 + d) * HID + h];
        #pragma unroll
        for (int d = 0; d < 20; d++) acc += se[si*20 + d] * W1[(size_t)(1576 + d) * HID + h];
    }
    PhiW[c * HIDP + h] = acc;
}

// ---------------------------------------------------------------- phase 1: Am = g_i@W1_a, Aa = g_i@W1_b  (blockIdx.y selects), bf16 out
__global__ __launch_bounds__(256) void k_proj(const unsigned short* __restrict__ g_bf,
                                              const unsigned short* __restrict__ WT,
                                              unsigned short* __restrict__ out){
    const unsigned short* Wh = WT + (size_t)blockIdx.y * 160 * 512;
    unsigned short* outh = out + (size_t)blockIdx.y * NROWS * HIDP;
    __shared__ short A_lds[64 * 72];
    __shared__ short B_lds[160 * 72];
    int tid = threadIdx.x, lane = tid & 63, w = tid >> 6;
    int row0 = blockIdx.x * 64;
    f32x4 acc[10];
    #pragma unroll
    for (int t = 0; t < 10; t++) acc[t] = (f32x4){0.f, 0.f, 0.f, 0.f};

    for (int kt = 0; kt < GDIM; kt += 64){
        #pragma unroll
        for (int i = 0; i < 2; i++){
            int c = tid + 256 * i; int r = c >> 3, off = c & 7;
            int row = row0 + r; if (row > NROWS - 1) row = NROWS - 1;
            *reinterpret_cast<bf16x8*>(&A_lds[r * 72 + off * 8]) =
                *reinterpret_cast<const bf16x8*>(&g_bf[(size_t)row * GDIM + kt + off * 8]);
        }
        #pragma unroll
        for (int i = 0; i < 5; i++){
            int c = tid + 256 * i; int n = c >> 3, off = c & 7;
            *reinterpret_cast<bf16x8*>(&B_lds[n * 72 + off * 8]) =
                *reinterpret_cast<const bf16x8*>(&Wh[(size_t)n * 512 + kt + off * 8]);
        }
        __syncthreads();
        #pragma unroll
        for (int kh = 0; kh < 2; kh++){
            bf16x8 a = *reinterpret_cast<const bf16x8*>(&A_lds[(16*w + (lane & 15)) * 72 + kh*32 + 8*(lane >> 4)]);
            #pragma unroll
            for (int t = 0; t < 10; t++){
                bf16x8 b = *reinterpret_cast<const bf16x8*>(&B_lds[(16*t + (lane & 15)) * 72 + kh*32 + 8*(lane >> 4)]);
                acc[t] = __builtin_amdgcn_mfma_f32_16x16x32_bf16(a, b, acc[t], 0, 0, 0);
            }
        }
        __syncthreads();
    }
    #pragma unroll
    for (int t = 0; t < 10; t++){
        #pragma unroll
        for (int i = 0; i < 4; i++){
            int r = 16*w + 4*(lane >> 4) + i;
            int row = row0 + r;
            if (row < NROWS) outh[(size_t)row * HIDP + 16*t + (lane & 15)] = f2bf(acc[t][i]);
        }
    }
}

// ---------------------------------------------------------------- phase 2+3 fused: product GEMM + epilogue + layer2 GEMM + W3 dot + scatter
__global__ __launch_bounds__(256) void k_fused(
    const unsigned short* __restrict__ g_bf, const float* __restrict__ ms,
    const unsigned short* __restrict__ W1cT, const unsigned short* __restrict__ W2T,
    const float* __restrict__ PhiW, const unsigned short* __restrict__ Am, const unsigned short* __restrict__ Aa,
    const float* __restrict__ W3, const float* __restrict__ b2, const float* __restrict__ b3,
    const int* __restrict__ mention_ids, const int* __restrict__ antecedent_ids,
    const int* __restrict__ dist_idx, const int* __restrict__ genre_idx, const int* __restrict__ spk_idx,
    const int* __restrict__ seg_ids, const int* __restrict__ pos_in_seg,
    float* __restrict__ dense, int P)
{
    __shared__ short smem[17152];          // 34304 B, regions time-shared
    short* A_lds  = smem;                  // [64][72]   GEMM1
    short* B_lds  = smem + 4608;           // [160][72]  GEMM1
    short* H1_lds = smem;                  // [64][168]  GEMM2 A (overlaps dead A/B)
    short* B2_lds = smem + 10752;          // [160][40]  GEMM2 B
    __shared__ int mids[64], aids[64], combos[64];

    int tid = threadIdx.x, lane = tid & 63, w = tid >> 6;
    int p0 = blockIdx.x * 64;

    if (tid < 64){
        int p = p0 + tid; int pc = (p < P) ? p : P - 1;
        mids[tid]   = mention_ids[pc];
        aids[tid]   = antecedent_ids[pc];
        combos[tid] = (dist_idx[pc] * 7 + genre_idx[pc]) * 3 + spk_idx[pc];
    }
    __syncthreads();

    f32x4 acc1[10];
    #pragma unroll
    for (int t = 0; t < 10; t++) acc1[t] = (f32x4){0.f, 0.f, 0.f, 0.f};

    for (int kt = 0; kt < GDIM; kt += 64){
        // A tile: products (i_g ⊙ j_g), gathered bf16, product in f32, repacked bf16
        #pragma unroll
        for (int i = 0; i < 2; i++){
            int c = tid + 256 * i; int r = c >> 3, off = c & 7;
            bf16x8 m = *reinterpret_cast<const bf16x8*>(&g_bf[(size_t)mids[r] * GDIM + kt + off * 8]);
            bf16x8 a = *reinterpret_cast<const bf16x8*>(&g_bf[(size_t)aids[r] * GDIM + kt + off * 8]);
            bf16x8 v;
            #pragma unroll
            for (int j = 0; j < 8; j++){
                float fm = bf2f((unsigned short)m[j]);
                float fa = bf2f((unsigned short)a[j]);
                v[j] = (short)f2bf(fm * fa);
            }
            *reinterpret_cast<bf16x8*>(&A_lds[r * 72 + off * 8]) = v;
        }
        // B tile: W1c^T chunk (pre-cast bf16)
        #pragma unroll
        for (int i = 0; i < 5; i++){
            int c = tid + 256 * i; int n = c >> 3, off = c & 7;
            *reinterpret_cast<bf16x8*>(&B_lds[n * 72 + off * 8]) =
                *reinterpret_cast<const bf16x8*>(&W1cT[(size_t)n * 512 + kt + off * 8]);
        }
        __syncthreads();
        #pragma unroll
        for (int kh = 0; kh < 2; kh++){
            bf16x8 a = *reinterpret_cast<const bf16x8*>(&A_lds[(16*w + (lane & 15)) * 72 + kh*32 + 8*(lane >> 4)]);
            #pragma unroll
            for (int t = 0; t < 10; t++){
                bf16x8 b = *reinterpret_cast<const bf16x8*>(&B_lds[(16*t + (lane & 15)) * 72 + kh*32 + 8*(lane >> 4)]);
                acc1[t] = __builtin_amdgcn_mfma_f32_16x16x32_bf16(a, b, acc1[t], 0, 0, 0);
            }
        }
        __syncthreads();
    }

    // epilogue 1: + Am + Aa + PhiW(+b1), relu, -> H1 in LDS (bf16)
    #pragma unroll
    for (int i = 0; i < 4; i++){
        int r = 16*w + 4*(lane >> 4) + i;
        int mid = mids[r], aid = aids[r], cmb = combos[r];
        #pragma unroll
        for (int t = 0; t < 10; t++){
            int h = 16*t + (lane & 15);
            float v = acc1[t][i] + bf2f(Am[(size_t)mid * HIDP + h]) + bf2f(Aa[(size_t)aid * HIDP + h])
                    + PhiW[cmb * HIDP + h];
            v = fmaxf(v, 0.f);
            H1_lds[r * 168 + h] = (short)f2bf(v);
        }
    }
    __syncthreads();

    // GEMM2: H2 = H1 @ W2 (K = 160, in 5 chunks of 32)
    f32x4 acc2[10];
    #pragma unroll
    for (int t = 0; t < 10; t++) acc2[t] = (f32x4){0.f, 0.f, 0.f, 0.f};

    for (int kt2 = 0; kt2 < HIDP; kt2 += 32){
        #pragma unroll
        for (int i = 0; i < 3; i++){
            int c = tid + 256 * i;
            if (c < 640){
                int n = c >> 2, off = c & 3;
                *reinterpret_cast<bf16x8*>(&B2_lds[n * 40 + off * 8]) =
                    *reinterpret_cast<const bf16x8*>(&W2T[(size_t)n * HIDP + kt2 + off * 8]);
            }
        }
        __syncthreads();
        bf16x8 a = *reinterpret_cast<const bf16x8*>(&H1_lds[(16*w + (lane & 15)) * 168 + kt2 + 8*(lane >> 4)]);
        #pragma unroll
        for (int t = 0; t < 10; t++){
            bf16x8 b = *reinterpret_cast<const bf16x8*>(&B2_lds[(16*t + (lane & 15)) * 40 + 8*(lane >> 4)]);
            acc2[t] = __builtin_amdgcn_mfma_f32_16x16x32_bf16(a, b, acc2[t], 0, 0, 0);
        }
        __syncthreads();
    }

    // epilogue 2: relu(+b2), dot W3, + mention scores, scatter into dense
    float w3v[10], b2v[10];
    #pragma unroll
    for (int t = 0; t < 10; t++){
        int h = 16*t + (lane & 15);
        w3v[t] = (h < HID) ? W3[h] : 0.f;
        b2v[t] = (h < HID) ? b2[h] : 0.f;
    }
    float b3v = b3[0];
    #pragma unroll
    for (int i = 0; i < 4; i++){
        float s = 0.f;
        #pragma unroll
        for (int t = 0; t < 10; t++) s += fmaxf(acc2[t][i] + b2v[t], 0.f) * w3v[t];
        s += __shfl_xor(s, 1, 16);
        s += __shfl_xor(s, 2, 16);
        s += __shfl_xor(s, 4, 16);
        s += __shfl_xor(s, 8, 16);
        int r = 16*w + 4*(lane >> 4) + i;
        int p = p0 + r;
        if (p < P && (lane & 15) == 0){
            float val = s + b3v + ms[mids[r]] + ms[aids[r]];
            dense[(size_t)seg_ids[p] * KP1 + pos_in_seg[p]] = val;
        }
    }
}

// ---------------------------------------------------------------- phase 4: segment softmax, epsilon slot, 1000 padding
__global__ void k_softmax(const float* __restrict__ dense, const int* __restrict__ seg_lengths,
                          float* __restrict__ out, int S){
    int wid = threadIdx.x >> 6, lane = threadIdx.x & 63;
    int s = blockIdx.x * 4 + wid;
    if (s >= S) return;
    int len = seg_lengths[s];
    float ninf = -__builtin_inff();
    float val = ninf;
    if (lane < KP1) val = (lane < len) ? dense[(size_t)s * KP1 + lane] : ((lane == len) ? 0.f : ninf);
    float m = val;
    #pragma unroll
    for (int msk = 1; msk < 64; msk <<= 1) m = fmaxf(m, __shfl_xor(m, msk));
    float e = expf(val - m);
    float sum = e;
    #pragma unroll
    for (int msk = 1; msk < 64; msk <<= 1) sum += __shfl_xor(sum, msk);
    if (lane < KP1) out[(size_t)s * KP1 + lane] = (lane > len) ? 1000.f : (e / sum);
}

// ---------------------------------------------------------------- launch
extern "C" void kernel_launch(void* const* d_in, const int* in_sizes, int n_in,
                              void* d_out, int out_size, void* d_ws, size_t ws_size,
                              hipStream_t stream){
    const float* g_i        = (const float*)d_in[0];
    const float* ms         = (const float*)d_in[1];
    const float* dist_emb   = (const float*)d_in[2];
    const float* genre_emb  = (const float*)d_in[3];
    const float* spk_emb    = (const float*)d_in[4];
    const float* W1         = (const float*)d_in[5];
    const float* b1         = (const float*)d_in[6];
    const float* W2         = (const float*)d_in[7];
    const float* b2         = (const float*)d_in[8];
    const float* W3         = (const float*)d_in[9];
    const float* b3         = (const float*)d_in[10];
    const int* mention_ids  = (const int*)d_in[11];
    const int* antecedent_ids = (const int*)d_in[12];
    const int* dist_idx     = (const int*)d_in[13];
    const int* genre_idx    = (const int*)d_in[14];
    const int* spk_idx      = (const int*)d_in[15];
    const int* seg_ids      = (const int*)d_in[16];
    const int* pos_in_seg   = (const int*)d_in[17];
    const int* seg_lengths  = (const int*)d_in[18];
    int P = in_sizes[11];
    int S = in_sizes[18];

    char* ws = (char*)d_ws;
    unsigned short* W1abT = (unsigned short*)(ws + 0);          // 320*512*2   = 327680
    unsigned short* W1cT  = (unsigned short*)(ws + 327680);     // 160*512*2   = 163840
    unsigned short* W2T   = (unsigned short*)(ws + 491520);     // 160*160*2   = 51200
    float* PhiW           = (float*)(ws + 542720);              // 210*160*4   = 134400 -> 677120
    unsigned short* g_bf  = (unsigned short*)(ws + 677120);     // 12000*512*2 = 12288000 -> 12965120
    unsigned short* AmAa  = (unsigned short*)(ws + 12965120);   // 2*12000*160*2 = 7680000 -> 20645120
    float* dense          = (float*)(ws + 20645120);            // 10001*31*4

    // weight / table prep
    k_cast_g<<<(NROWS*GDIM/8 + 255)/256, 256, 0, stream>>>(g_i, g_bf, NROWS*GDIM/8);
    k_castT<<<(160*512 + 255)/256, 256, 0, stream>>>(W1, W1abT,            160, 512, HID, 512, HID, 0);
    k_castT<<<(160*512 + 255)/256, 256, 0, stream>>>(W1, W1abT + 160*512,  160, 512, HID, 512, HID, 512);
    k_castT<<<(160*512 + 255)/256, 256, 0, stream>>>(W1, W1cT,             160, 512, HID, 512, HID, 1024);
    k_castT<<<(160*160 + 255)/256, 256, 0, stream>>>(W2, W2T,              160, 160, HID, HID, HID, 0);
    k_phiw<<<210, 192, 0, stream>>>(dist_emb, genre_emb, spk_emb, W1, b1, PhiW);

    // row projections Am / Aa (bf16 out)
    k_proj<<<dim3((NROWS + 63)/64, 2), 256, 0, stream>>>(g_bf, W1abT, AmAa);

    // fused pair scorer
    k_fused<<<(P + 63)/64, 256, 0, stream>>>(g_bf, ms, W1cT, W2T, PhiW,
        AmAa, AmAa + (size_t)NROWS*HIDP, W3, b2, b3,
        mention_ids, antecedent_ids, dist_idx, genre_idx, spk_idx,
        seg_ids, pos_in_seg, dense, P);

    // segment softmax
    k_softmax<<<(S + 3)/4, 256, 0, stream>>>(dense, seg_lengths, (float*)d_out, S);
}